// Round 2
// baseline (177.280 us; speedup 1.0000x reference)
//
#include <hip/hip_runtime.h>
#include <math.h>

#define BATCH 32
#define CH    3
#define H     512
#define W     512
#define KWIN  15
#define PAD   7
#define TH    32   // output rows per block

// Fused dark-channel + 15x15 min-pool (separable: h-min rows into a 15-deep
// LDS ring, then v-min over the full ring per output row).
__global__ __launch_bounds__(256) void dcp_fused(const float* __restrict__ I,
                                                 float* __restrict__ out) {
    const int b  = blockIdx.y;
    const int y0 = blockIdx.x * TH;
    const int t  = threadIdx.x;
    const int x  = t * 2;

    __shared__ float ring[KWIN][W];        // ring[(y+PAD)%15] = h-min of dark row y
    __shared__ float s[W + 2 * PAD + 2];   // staging: dark row + inf halo

    const float* base = I + (size_t)b * CH * H * W;

    auto insert_row = [&](int y) {
        const int slot = (y + PAD) % KWIN;   // y >= y0-PAD >= -PAD, so y+PAD >= 0
        if (y >= 0 && y < H) {
            const float2 a0 = *(const float2*)(base + ((size_t)(0 * H) + y) * W + x);
            const float2 a1 = *(const float2*)(base + ((size_t)(1 * H) + y) * W + x);
            const float2 a2 = *(const float2*)(base + ((size_t)(2 * H) + y) * W + x);
            s[PAD + x]     = fminf(fminf(a0.x, a1.x), a2.x);
            s[PAD + x + 1] = fminf(fminf(a0.y, a1.y), a2.y);
            if (t < PAD) {                   // +inf padding (min-pool equiv of -inf max-pool pad)
                s[t]           = INFINITY;
                s[PAD + W + t] = INFINITY;
            }
            __syncthreads();
            // window for col x: s[x .. x+14]; col x+1: s[x+1 .. x+15]
            const float p0 = fminf(s[x + 1],  s[x + 2]);
            const float p1 = fminf(s[x + 3],  s[x + 4]);
            const float p2 = fminf(s[x + 5],  s[x + 6]);
            const float p3 = fminf(s[x + 7],  s[x + 8]);
            const float p4 = fminf(s[x + 9],  s[x + 10]);
            const float p5 = fminf(s[x + 11], s[x + 12]);
            const float p6 = fminf(s[x + 13], s[x + 14]);
            const float q0 = fminf(p0, p1), q1 = fminf(p2, p3), q2 = fminf(p4, p5);
            const float common = fminf(fminf(q0, q1), fminf(q2, p6));
            ring[slot][x]     = fminf(common, s[x]);
            ring[slot][x + 1] = fminf(common, s[x + KWIN]);
        } else {                             // block-uniform branch
            ring[slot][x]     = INFINITY;
            ring[slot][x + 1] = INFINITY;
        }
    };

    // Prologue: rows y0-7 .. y0+6
    #pragma unroll 1
    for (int i = 0; i < KWIN - 1; ++i) {
        insert_row(y0 - PAD + i);
        __syncthreads();
    }

    #pragma unroll 1
    for (int r = 0; r < TH; ++r) {
        const int y = y0 + r;
        insert_row(y + PAD);
        __syncthreads();                     // ring fully updated

        // v-min over all 15 ring rows (window == ring size; order irrelevant)
        float2 v[KWIN];
        #pragma unroll
        for (int i = 0; i < KWIN; ++i) v[i] = *(const float2*)&ring[i][x];
        float mx0 = fminf(v[0].x, v[1].x),  my0 = fminf(v[0].y, v[1].y);
        float mx1 = fminf(v[2].x, v[3].x),  my1 = fminf(v[2].y, v[3].y);
        float mx2 = fminf(v[4].x, v[5].x),  my2 = fminf(v[4].y, v[5].y);
        float mx3 = fminf(v[6].x, v[7].x),  my3 = fminf(v[6].y, v[7].y);
        float mx4 = fminf(v[8].x, v[9].x),  my4 = fminf(v[8].y, v[9].y);
        float mx5 = fminf(v[10].x, v[11].x), my5 = fminf(v[10].y, v[11].y);
        float mx6 = fminf(v[12].x, v[13].x), my6 = fminf(v[12].y, v[13].y);
        mx0 = fminf(mx0, mx1); my0 = fminf(my0, my1);
        mx2 = fminf(mx2, mx3); my2 = fminf(my2, my3);
        mx4 = fminf(mx4, mx5); my4 = fminf(my4, my5);
        mx6 = fminf(mx6, v[14].x); my6 = fminf(my6, v[14].y);
        float2 o;
        o.x = fminf(fminf(mx0, mx2), fminf(mx4, mx6));
        o.y = fminf(fminf(my0, my2), fminf(my4, my6));
        *(float2*)(out + ((size_t)b * H + y) * W + x) = o;
        __syncthreads();                     // ring/stage safe to overwrite
    }
}

extern "C" void kernel_launch(void* const* d_in, const int* in_sizes, int n_in,
                              void* d_out, int out_size, void* d_ws, size_t ws_size,
                              hipStream_t stream) {
    const float* I = (const float*)d_in[0];
    // d_in[1] is k == 15, hard-coded (KWIN/PAD)
    float* out = (float*)d_out;
    dcp_fused<<<dim3(H / TH, BATCH), dim3(256), 0, stream>>>(I, out);
}

// Round 3
// 176.435 us; speedup vs baseline: 1.0048x; 1.0048x over previous
//
#include <hip/hip_runtime.h>
#include <math.h>

#define BATCH 32
#define CH    3
#define H     512
#define W     512
#define KWIN  15
#define PAD   7
#define TH    8    // output rows per block

// Fused dark-channel + 15x15 min-pool, vertical-first separable order.
// One __syncthreads per block. Van Herk sliding-min for the vertical pass.
__global__ __launch_bounds__(256, 8) void dcp_fused2(const float* __restrict__ I,
                                                     float* __restrict__ out) {
    const int b  = blockIdx.y;
    const int y0 = blockIdx.x * TH;
    const int t  = threadIdx.x;
    const int x  = t * 2;                       // this thread's 2 columns

    __shared__ float tile[TH][W + 2 * PAD + 2]; // v-min rows, +inf column halo

    const float* base = I + (size_t)b * CH * H * W;

    // channel-min of row y at this thread's 2 columns (+inf outside image)
    auto load_cm = [&](int y) -> float2 {
        float2 r;
        if (y < 0 || y >= H) { r.x = INFINITY; r.y = INFINITY; return r; } // block-uniform
        const float2 a0 = *(const float2*)(base + ((size_t)0 * H + y) * W + x);
        const float2 a1 = *(const float2*)(base + ((size_t)1 * H + y) * W + x);
        const float2 a2 = *(const float2*)(base + ((size_t)2 * H + y) * W + x);
        r.x = fminf(fminf(a0.x, a1.x), a2.x);
        r.y = fminf(fminf(a0.y, a1.y), a2.y);
        return r;
    };

    // v index i ∈ [0,22) maps to row y0 - PAD + i. Output r: min v[r..r+14].
    // Van Herk split at i=15: P[k] = min(v[15..15+k]) k=0..6; U[i] = min(v[i..14]).
    // o[r] = (r==0) ? U[0] : min(U[r], P[r-1]).
    float2 P[PAD];
    {
        float2 run = load_cm(y0 + 8);           // v[15]
        P[0] = run;
        #pragma unroll
        for (int k = 1; k < PAD; ++k) {
            const float2 c = load_cm(y0 + 8 + k);
            run.x = fminf(run.x, c.x); run.y = fminf(run.y, c.y);
            P[k] = run;
        }
    }
    float2 U = load_cm(y0 + 7);                 // v[14]
    #pragma unroll
    for (int i = 13; i >= 8; --i) {
        const float2 c = load_cm(y0 - PAD + i);
        U.x = fminf(U.x, c.x); U.y = fminf(U.y, c.y);
    }
    #pragma unroll
    for (int i = PAD; i >= 0; --i) {            // fold v[7]..v[0], emit o[7]..o[0]
        const float2 c = load_cm(y0 - PAD + i);
        U.x = fminf(U.x, c.x); U.y = fminf(U.y, c.y);
        float2 o;
        if (i > 0) { o.x = fminf(U.x, P[i - 1].x); o.y = fminf(U.y, P[i - 1].y); }
        else       { o = U; }
        *(float2*)&tile[i][PAD + x] = o;
    }

    // +inf column halo
    if (t < PAD) {
        #pragma unroll
        for (int r = 0; r < TH; ++r) tile[r][t] = INFINITY;
    } else if (t < 2 * PAD) {
        #pragma unroll
        for (int r = 0; r < TH; ++r) tile[r][W + t] = INFINITY;  // W+PAD+(t-PAD)
    }
    __syncthreads();                            // the only barrier

    // Horizontal 15-min from LDS: read 8 float2 (b64, conflict-free),
    // shared middle = min over padded cols x+1..x+14.
    #pragma unroll
    for (int r = 0; r < TH; ++r) {
        float2 w[8];
        #pragma unroll
        for (int j = 0; j < 8; ++j) w[j] = *(const float2*)&tile[r][x + 2 * j];
        float m = fminf(w[0].y, w[7].x);
        #pragma unroll
        for (int j = 1; j < 7; ++j) m = fminf(m, fminf(w[j].x, w[j].y));
        float2 o;
        o.x = fminf(m, w[0].x);                 // cols x-7..x+7
        o.y = fminf(m, w[7].y);                 // cols x-6..x+8
        *(float2*)(out + ((size_t)b * H + y0 + r) * W + x) = o;
    }
}

extern "C" void kernel_launch(void* const* d_in, const int* in_sizes, int n_in,
                              void* d_out, int out_size, void* d_ws, size_t ws_size,
                              hipStream_t stream) {
    const float* I = (const float*)d_in[0];
    // d_in[1] is k == 15, hard-coded (KWIN/PAD)
    float* out = (float*)d_out;
    dcp_fused2<<<dim3(H / TH, BATCH), dim3(256), 0, stream>>>(I, out);
}